// Round 1
// baseline (164.812 us; speedup 1.0000x reference)
//
#include <hip/hip_runtime.h>

// Problem constants
#define NB 64
#define NP 500
#define NC 128
#define NH 256
#define EPS_BN 1e-5f

// Edge-list geometry: 64 batches x 8 j-tiles, cap 1024 edges/segment
// (expected ~120 i<j edges per segment for uniform points; 8x margin)
#define SEGS 8
#define CAPE 1024

// ws layout (float/int words)
#define EDGE_OFF 0
#define EDGE_WORDS (NB * SEGS * CAPE)            // 524288
#define CNT_OFF (EDGE_OFF + EDGE_WORDS)          // 524288, 512 words
#define CT_OFF (CNT_OFF + 512)                   // c matrix, feature-major [256][64]
#define H1_OFF (CT_OFF + NH * NB)
#define H2_OFF (H1_OFF + NH * NB)
// total ~574K words = 2.3 MB of ws

// Output layout: tc[64] | tsys[64] | l2_points[4096000] | correlation[8192]
#define OUT_PTS_OFF 128
#define OUT_CORR_OFF 4096128

#define COPY_BLKS 768
#define TOTAL_F4 1024000  // 4,096,000 floats / 4

// ---------------------------------------------------------------------------
// K1: pair scan (blocks 0..511) + per-batch misc (512..575) + copy half 1
// ---------------------------------------------------------------------------
__global__ __launch_bounds__(256) void k1_scan_misc_copy(
    const float* __restrict__ xyz,    // [B,3,N]
    const float* __restrict__ temp,   // [B,1,N]
    const float* __restrict__ l3,     // [B,C]
    const float* __restrict__ b4,     // [1] fc_lt4_b
    const float* __restrict__ pts,    // [B,C,N] l2_points
    float* __restrict__ out,
    float* __restrict__ ws) {
  const int blk = blockIdx.x;
  const int tid = threadIdx.x;

  if (blk < 512) {
    // -------- pair scan: batch b, j-tile jt, strictly upper (i<j) ---------
    const int b = blk >> 3;
    const int jt = blk & 7;
    __shared__ float4 pt[NP];  // x,y,z,s
    __shared__ int lcnt;
    if (tid == 0) lcnt = 0;
    const float* xr = xyz + b * 1500;
    for (int idx = tid; idx < NP; idx += 256) {
      float x = xr[idx], y = xr[500 + idx], z = xr[1000 + idx];
      float s = x * x + y * y + z * z;  // match ref jnp.sum(point*point)
      pt[idx] = make_float4(x, y, z, s);
    }
    __syncthreads();

    const int j0 = jt * 63;
    const int j1 = (j0 + 63 < NP) ? j0 + 63 : NP;
    const int i0 = tid;
    const int i1 = tid + 256;
    float4 p0 = pt[i0];
    float4 p1 = (i1 < NP) ? pt[i1] : make_float4(0.f, 0.f, 0.f, 0.f);
    int* eseg = (int*)ws + EDGE_OFF + (b * SEGS + jt) * CAPE;

    for (int j = j0; j < j1; ++j) {
      float4 q = pt[j];  // wave-uniform -> LDS broadcast
      if (i0 < j) {
        float dot = p0.x * q.x + p0.y * q.y + p0.z * q.z;
        float sq = p0.w + q.w - 2.f * dot;
        float d = sqrtf(fabsf(sq));
        if (d > 0.19f && d < 0.21f) {
          int e = atomicAdd(&lcnt, 1);
          if (e < CAPE) eseg[e] = (i0 << 16) | j;
        }
      }
      if (i1 < j) {  // implies i1 < 500
        float dot = p1.x * q.x + p1.y * q.y + p1.z * q.z;
        float sq = p1.w + q.w - 2.f * dot;
        float d = sqrtf(fabsf(sq));
        if (d > 0.19f && d < 0.21f) {
          int e = atomicAdd(&lcnt, 1);
          if (e < CAPE) eseg[e] = (i1 << 16) | j;
        }
      }
    }
    __syncthreads();
    if (tid == 0) {
      int c = lcnt < CAPE ? lcnt : CAPE;
      ((int*)ws)[CNT_OFF + b * SEGS + jt] = c;
    }
  } else if (blk < 576) {
    // -------- misc per batch: tsys, cT sa4 rows, tc bias init -------------
    const int b = blk - 512;
    float sum = 0.f;
    for (int i = tid; i < NP; i += 256) sum += temp[b * NP + i];
    for (int off = 32; off; off >>= 1) sum += __shfl_xor(sum, off);
    __shared__ float wsum[4];
    if ((tid & 63) == 0) wsum[tid >> 6] = sum;
    __syncthreads();
    if (tid == 0)
      out[64 + b] = (wsum[0] + wsum[1] + wsum[2] + wsum[3]) * (1.f / 500.f);
    if (tid < 128) ws[CT_OFF + (128 + tid) * 64 + b] = l3[b * NC + tid];
    if (tid == 0) out[b] = b4[0];  // tc starts at bias; layer-lt1 atomicAdds
  } else {
    // -------- copy half 1 of l2_points -> out ----------------------------
    const int cb = blk - 576;
    const float4* src = (const float4*)pts;
    float4* dst = (float4*)(out + OUT_PTS_OFF);
    for (int idx = cb * 256 + tid; idx < TOTAL_F4 / 2; idx += COPY_BLKS * 256)
      dst[idx] = src[idx];
  }
}

// ---------------------------------------------------------------------------
// K2: correlation accumulation (blocks 0..511: 64 batches x 8 chan-groups)
//     + copy half 2
// ---------------------------------------------------------------------------
__global__ __launch_bounds__(256) void k2_corr_copy(
    const float* __restrict__ data,  // l2_points [B,C,N]
    float* __restrict__ out,
    float* __restrict__ ws) {
  const int blk = blockIdx.x;
  const int tid = threadIdx.x;

  if (blk < 512) {
    const int b = blk >> 3;
    const int c0 = (blk & 7) * 16;
    __shared__ float dT[NP * 20];  // [j][c] for 16 channels, stride 20 (16B-aligned quads, odd-ish banking)
    __shared__ float corrp[16];
    if (tid < 16) corrp[tid] = 0.f;

    // stage 16 contiguous channel rows, transposed
    const float4* in4 = (const float4*)(data + (size_t)b * 64000 + c0 * 500);
    for (int idx = tid; idx < 2000; idx += 256) {
      float4 v = in4[idx];
      int c = idx / 125;
      int j = (idx - c * 125) * 4;
      dT[(j + 0) * 20 + c] = v.x;
      dT[(j + 1) * 20 + c] = v.y;
      dT[(j + 2) * 20 + c] = v.z;
      dT[(j + 3) * 20 + c] = v.w;
    }
    __syncthreads();

    const int quad = tid & 3;    // which 4-channel group
    const int slot = tid >> 2;   // 64 edge slots
    float4 acc = make_float4(0.f, 0.f, 0.f, 0.f);
    const int* cnts = (const int*)ws + CNT_OFF + b * SEGS;
    int Etot = 0;
    for (int seg = 0; seg < SEGS; ++seg) {
      int E = cnts[seg];
      Etot += E;
      const int* eseg = (const int*)ws + EDGE_OFF + (b * SEGS + seg) * CAPE;
      for (int e = slot; e < E; e += 64) {
        int ij = eseg[e];
        int i = ij >> 16, j = ij & 0xffff;
        const float4 a = *(const float4*)(dT + i * 20 + quad * 4);
        const float4 c4 = *(const float4*)(dT + j * 20 + quad * 4);
        acc.x += a.x * c4.x;
        acc.y += a.y * c4.y;
        acc.z += a.z * c4.z;
        acc.w += a.w * c4.w;
      }
    }
    // reduce over slots within wave (offsets 4..32 preserve quad)
    for (int off = 4; off < 64; off <<= 1) {
      acc.x += __shfl_xor(acc.x, off);
      acc.y += __shfl_xor(acc.y, off);
      acc.z += __shfl_xor(acc.z, off);
      acc.w += __shfl_xor(acc.w, off);
    }
    if ((tid & 63) < 4) {  // lanes 0..3 of each wave hold quad 0..3 totals
      atomicAdd(&corrp[quad * 4 + 0], acc.x);
      atomicAdd(&corrp[quad * 4 + 1], acc.y);
      atomicAdd(&corrp[quad * 4 + 2], acc.z);
      atomicAdd(&corrp[quad * 4 + 3], acc.w);
    }
    __syncthreads();
    if (tid < 16) {
      // mask symmetric: ordered count = 2E, ordered sum = 2 * upper sum
      float denom = fmaxf(2.f * (float)Etot, 1.f);
      float v = 2.f * corrp[tid] / denom;
      out[OUT_CORR_OFF + b * NC + c0 + tid] = v;
      ws[CT_OFF + (c0 + tid) * 64 + b] = v;
    }
  } else {
    const int cb = blk - 512;
    const float4* src = (const float4*)data;
    float4* dst = (float4*)(out + OUT_PTS_OFF);
    for (int idx = TOTAL_F4 / 2 + cb * 256 + tid; idx < TOTAL_F4;
         idx += COPY_BLKS * 256)
      dst[idx] = src[idx];
  }
}

// ---------------------------------------------------------------------------
// Layer: y = relu(BN(x @ W^T + bias)); BN over batch dim (64 = one wave).
// Grid: 256 blocks (one output feature) x 256 threads (4 waves split K).
// Activations feature-major [256][64] for coalescing.
// If w4 != null: instead of storing, atomicAdd w4[o]*h into tc[b].
// ---------------------------------------------------------------------------
__global__ __launch_bounds__(256) void layer_k(
    const float* __restrict__ xT, const float* __restrict__ W,
    const float* __restrict__ bias, const float* __restrict__ g,
    const float* __restrict__ be, float* __restrict__ yT,
    const float* __restrict__ w4, float* __restrict__ tc) {
  const int o = blockIdx.x;
  const int b = threadIdx.x & 63;
  const int w = threadIdx.x >> 6;
  const float* wr = W + o * NH + w * 64;
  const float* xp = xT + (w * 64) * 64 + b;
  float acc = 0.f;
#pragma unroll
  for (int i = 0; i < 64; ++i) acc += xp[i * 64] * wr[i];
  __shared__ float part[4][64];
  part[w][b] = acc;
  __syncthreads();
  if (w == 0) {
    float t = part[0][b] + part[1][b] + part[2][b] + part[3][b] + bias[o];
    float s1 = t;
    for (int off = 32; off; off >>= 1) s1 += __shfl_xor(s1, off);
    float m = s1 * (1.f / 64.f);
    float d = t - m;
    float s2 = d * d;
    for (int off = 32; off; off >>= 1) s2 += __shfl_xor(s2, off);
    float var = s2 * (1.f / 64.f);
    float h = g[o] * d * rsqrtf(var + EPS_BN) + be[o];
    h = fmaxf(h, 0.f);
    if (w4) {
      atomicAdd(&tc[b], w4[o] * h);
    } else {
      yT[o * 64 + b] = h;
    }
  }
}

extern "C" void kernel_launch(void* const* d_in, const int* in_sizes, int n_in,
                              void* d_out, int out_size, void* d_ws,
                              size_t ws_size, hipStream_t stream) {
  const float* xyz = (const float*)d_in[0];
  const float* pts = (const float*)d_in[1];
  const float* l3 = (const float*)d_in[2];
  const float* temp = (const float*)d_in[3];
  const float* w0 = (const float*)d_in[4];
  const float* b0 = (const float*)d_in[5];
  const float* g0 = (const float*)d_in[6];
  const float* be0 = (const float*)d_in[7];
  const float* w1 = (const float*)d_in[8];
  const float* b1 = (const float*)d_in[9];
  const float* g1 = (const float*)d_in[10];
  const float* be1 = (const float*)d_in[11];
  const float* w2 = (const float*)d_in[12];
  const float* b2 = (const float*)d_in[13];
  const float* g2 = (const float*)d_in[14];
  const float* be2 = (const float*)d_in[15];
  const float* w3 = (const float*)d_in[16];
  const float* b3 = (const float*)d_in[17];
  const float* g3 = (const float*)d_in[18];
  const float* be3 = (const float*)d_in[19];
  const float* w4 = (const float*)d_in[20];
  const float* b4 = (const float*)d_in[21];

  float* out = (float*)d_out;
  float* ws = (float*)d_ws;
  float* cT = ws + CT_OFF;
  float* hA = ws + H1_OFF;
  float* hB = ws + H2_OFF;

  k1_scan_misc_copy<<<576 + COPY_BLKS, 256, 0, stream>>>(xyz, temp, l3, b4,
                                                         pts, out, ws);
  k2_corr_copy<<<512 + COPY_BLKS, 256, 0, stream>>>(pts, out, ws);
  layer_k<<<256, 256, 0, stream>>>(cT, w0, b0, g0, be0, hA, nullptr, nullptr);
  layer_k<<<256, 256, 0, stream>>>(hA, w1, b1, g1, be1, hB, nullptr, nullptr);
  layer_k<<<256, 256, 0, stream>>>(hB, w2, b2, g2, be2, hA, nullptr, nullptr);
  layer_k<<<256, 256, 0, stream>>>(hA, w3, b3, g3, be3, nullptr, w4, out);
}